// Round 20
// baseline (67.241 us; speedup 1.0000x reference)
//
#include <hip/hip_runtime.h>
#include <hip/hip_bf16.h>

// Problem constants (from reference)
#define B 8
#define C 64
#define H 64
#define W 64
#define K 5
#define PAD 2
#define HW (H * W)          // 4096
#define CHW (C * HW)        // 262144
#define TOT (B * CHW)       // 2097152

// attn tiling: block = 16 rows x 64 cols of one (b,c) plane
#define TROWS 16
#define SROWS (TROWS + 2 * PAD)   // 20 staged rows
#define SCOLS 72                  // 64 + 2*PAD, padded to 72 for 16B row alignment

#define LOG2E 1.44269504088896340736f

typedef __attribute__((ext_vector_type(8))) short short8;   // 8 bf16 = 4 VGPR
typedef __attribute__((ext_vector_type(4))) float f32x4;    // mfma accum

// native bf16 conversion (RNE; pairs lower to v_cvt_pk_bf16_f32)
__device__ inline unsigned short f2bf(float f) {
    __hip_bfloat16 h = __float2bfloat16(f);
    return *(unsigned short*)&h;
}
__device__ inline float bf2f(unsigned short u) {
    return __uint_as_float(((unsigned)u) << 16);
}

// raw v_exp_f32 (single instruction; inputs in [-40,40])
__device__ inline float fast_exp2(float x) {
    return __builtin_amdgcn_exp2f(x);
}

// ---------------------------------------------------------------------------
// Pass 1 (v10): qkv MFMA GEMM — byte-identical to r17 (best: 28.9 us).
// ---------------------------------------------------------------------------
__global__ __launch_bounds__(256) void qkv_mfma(
    const float* __restrict__ x,
    const float* __restrict__ Wq,
    const float* __restrict__ Wk,
    const float* __restrict__ Wv,
    float* __restrict__ qb, float* __restrict__ kb, float* __restrict__ vb)
{
    __shared__ unsigned short sxh[32][72];   // [n][k], 4.6 KB
    __shared__ unsigned short sxl[32][72];

    const int bid = blockIdx.x;
    const int b   = bid & 7;             // XCD co-residency: batch = XCD
    const int n0  = (bid >> 3) * 32;     // hw base (128 chunks per batch)
    const int t   = threadIdx.x;

    const float* xb = x + b * CHW;
#pragma unroll
    for (int i = 0; i < 2; ++i) {
        const int flat = t + i * 256;        // 0..511
        const int k    = flat >> 3;          // 8 float4 per k-row of 32
        const int n4   = (flat & 7) << 2;
        const float4 v = *(const float4*)(xb + k * HW + n0 + n4);
        const float vv[4] = {v.x, v.y, v.z, v.w};
#pragma unroll
        for (int j = 0; j < 4; ++j) {
            const unsigned short h = f2bf(vv[j]);
            sxh[n4 + j][k] = h;
            sxl[n4 + j][k] = f2bf(vv[j] - bf2f(h));
        }
    }
    __syncthreads();

    const int lane = t & 63;
    const int wv   = __builtin_amdgcn_readfirstlane(t >> 6);  // wave id 0..3
    const int lr   = lane & 15;          // tile row (A) / col (B,D)
    const int lk   = (lane >> 4) * 8;    // k-group base

    short8 ah[3][2], al[3][2];
#pragma unroll
    for (int ot = 0; ot < 3; ++ot) {
        const int tile = wv * 3 + ot;            // 0..11
        const int m    = tile >> 2;              // 0=q,1=k,2=v
        const int ol0  = (tile & 3) * 16;        // o base within matrix
        const float* Wm = (m == 0) ? Wq : (m == 1) ? Wk : Wv;
        const float* wrow = Wm + (ol0 + lr) * 64;
#pragma unroll
        for (int ks = 0; ks < 2; ++ks) {
            const float4 w0 = *(const float4*)(wrow + lk + ks * 32);
            const float4 w1 = *(const float4*)(wrow + lk + ks * 32 + 4);
            const float wv8[8] = {w0.x, w0.y, w0.z, w0.w,
                                  w1.x, w1.y, w1.z, w1.w};
            short8 hi, lo;
#pragma unroll
            for (int j = 0; j < 8; ++j) {
                const unsigned short hh = f2bf(wv8[j]);
                hi[j] = (short)hh;
                lo[j] = (short)f2bf(wv8[j] - bf2f(hh));
            }
            ah[ot][ks] = hi;
            al[ot][ks] = lo;
        }
    }

    f32x4 acc[3][2];
#pragma unroll
    for (int ot = 0; ot < 3; ++ot)
#pragma unroll
        for (int nt = 0; nt < 2; ++nt) acc[ot][nt] = (f32x4)0.f;

#pragma unroll
    for (int nt = 0; nt < 2; ++nt) {
        const short8 bh0 = *(const short8*)&sxh[nt * 16 + lr][lk];
        const short8 bh1 = *(const short8*)&sxh[nt * 16 + lr][32 + lk];
        const short8 bl0 = *(const short8*)&sxl[nt * 16 + lr][lk];
        const short8 bl1 = *(const short8*)&sxl[nt * 16 + lr][32 + lk];
#pragma unroll
        for (int ot = 0; ot < 3; ++ot) {
            f32x4 d = acc[ot][nt];
            d = __builtin_amdgcn_mfma_f32_16x16x32_bf16(ah[ot][0], bh0, d, 0, 0, 0);
            d = __builtin_amdgcn_mfma_f32_16x16x32_bf16(ah[ot][1], bh1, d, 0, 0, 0);
            d = __builtin_amdgcn_mfma_f32_16x16x32_bf16(ah[ot][0], bl0, d, 0, 0, 0);
            d = __builtin_amdgcn_mfma_f32_16x16x32_bf16(ah[ot][1], bl1, d, 0, 0, 0);
            d = __builtin_amdgcn_mfma_f32_16x16x32_bf16(al[ot][0], bh0, d, 0, 0, 0);
            d = __builtin_amdgcn_mfma_f32_16x16x32_bf16(al[ot][1], bh1, d, 0, 0, 0);
            acc[ot][nt] = d;
        }
    }

#pragma unroll
    for (int ot = 0; ot < 3; ++ot) {
        const int tile = wv * 3 + ot;
        const int m    = tile >> 2;
        const int ol0  = (tile & 3) * 16;
        float* ob = (m == 0) ? qb : (m == 1) ? kb : vb;
        float* basep = ob + b * CHW + ol0 * HW + n0;
#pragma unroll
        for (int nt = 0; nt < 2; ++nt)
#pragma unroll
            for (int r = 0; r < 4; ++r) {
                const int orow = (lane >> 4) * 4 + r;
                basep[orow * HW + nt * 16 + lr] = acc[ot][nt][r];
            }
    }
}

// ---------------------------------------------------------------------------
// Pass 2 (v8): attn — r17 structure with __launch_bounds__(256, 8):
// forces <=64 VGPR so 8 blocks/CU fit (32 waves/CU cap) and the 2048-block
// grid executes in EXACTLY ONE resident round (at 6 waves/SIMD it was 1.33
// ragged rounds -> +33-50% wall time).  Inner loop restructured to shrink
// live ranges: float4s consumed directly, no kr[8]/vr[8] staging arrays.
// ---------------------------------------------------------------------------
__global__ __launch_bounds__(256, 8) void attn_kernel(
    const float* __restrict__ qb,
    const float* __restrict__ kb,
    const float* __restrict__ vb,
    const float* __restrict__ rel_h,
    const float* __restrict__ rel_w,
    float* __restrict__ out)
{
    __shared__ __align__(16) float sk[SROWS][SCOLS];
    __shared__ __align__(16) float sv[SROWS][SCOLS];

    const int bid = blockIdx.x;
    const int b   = bid & 7;           // XCD co-residency: batch = XCD
    const int u   = bid >> 3;          // 0..255: chan*4 + rowtile
    const int c   = u >> 2;
    const int pl  = b * C + c;
    const int h0  = (u & 3) * TROWS;
    const int t   = threadIdx.x;

    const int lr = t >> 4;             // local row 0..15
    const int w0 = (t & 15) << 2;      // col base 0,4,..,60
    const int h  = h0 + lr;

    // hoisted q load: latency hides under the stage
    const float4 qv = *(const float4*)(qb + pl * HW + h * W + w0);

    const float* kp = kb + pl * HW;
    const float* vp = vb + pl * HW;

    // ---- stage interior: 2 planes * 640 float2 slots (pow-2 mapping) ----
#pragma unroll
    for (int i = 0; i < 5; ++i) {
        const int s  = t + i * 256;          // 0..1279
        const int p  = (s >= 640);
        const int s2 = p ? s - 640 : s;
        const int row = s2 >> 5;             // 0..19
        const int c2  = s2 & 31;             // f2 slot within row
        const int g   = h0 + row - PAD;      // global row
        float2 val = make_float2(0.f, 0.f);
        if ((unsigned)g < (unsigned)H)
            val = *(const float2*)((p ? vp : kp) + g * W + c2 * 2);
        float* dst = (p ? &sv[0][0] : &sk[0][0]) + row * SCOLS + 2 + c2 * 2;
        *(float2*)dst = val;
    }
    // ---- halo ring zero: cols {0,1} and {66..71} of all 20 rows ----
    if (t < 160) {
        const int p   = (t >= 80);
        const int s   = p ? t - 80 : t;
        const int row = s >> 2;              // 0..19
        const int e   = s & 3;               // 0 -> col 0; 1..3 -> 66,68,70
        const int col = (e == 0) ? 0 : (64 + 2 * e);
        float* dst = (p ? &sv[0][0] : &sk[0][0]) + row * SCOLS + col;
        *(float2*)dst = make_float2(0.f, 0.f);
    }
    __syncthreads();

    const float qe[4] = {qv.x * LOG2E, qv.y * LOG2E, qv.z * LOG2E, qv.w * LOG2E};

    const bool is_h = (c < (C / 2));
    const float* rp = is_h ? (rel_h + c * K) : (rel_w + (c - C / 2) * K);
    float r[K];
#pragma unroll
    for (int u2 = 0; u2 < K; ++u2) r[u2] = rp[u2];

    float den[4] = {0.f, 0.f, 0.f, 0.f};
    float num[4] = {0.f, 0.f, 0.f, 0.f};

#pragma unroll
    for (int i = 0; i < K; ++i) {
        const float4 ka = *(const float4*)&sk[lr + i][w0];
        const float4 kc = *(const float4*)&sk[lr + i][w0 + 4];
        const float4 va = *(const float4*)&sv[lr + i][w0];
        const float4 vc = *(const float4*)&sv[lr + i][w0 + 4];
        // bias term: is_h is block-uniform; qbias[px][j] needed per tap
        float qbi[4];                       // is_h: qe*r[i] per px
#pragma unroll
        for (int px = 0; px < 4; ++px) qbi[px] = qe[px] * r[i];

#pragma unroll
        for (int j = 0; j < K; ++j) {
            // window values for pixels 0..3 at tap j: cols w0+j .. w0+j+3
            const float kj0 = (j < 4) ? ((const float*)&ka)[j]     : kc.x;
            const float kj1 = (j < 3) ? ((const float*)&ka)[j + 1] : ((const float*)&kc)[j - 3];
            const float kj2 = (j < 2) ? ((const float*)&ka)[j + 2] : ((const float*)&kc)[j - 2];
            const float kj3 = (j < 1) ? ((const float*)&ka)[j + 3] : ((const float*)&kc)[j - 1];
            const float vj0 = (j < 4) ? ((const float*)&va)[j]     : vc.x;
            const float vj1 = (j < 3) ? ((const float*)&va)[j + 1] : ((const float*)&vc)[j - 3];
            const float vj2 = (j < 2) ? ((const float*)&va)[j + 2] : ((const float*)&vc)[j - 2];
            const float vj3 = (j < 1) ? ((const float*)&va)[j + 3] : ((const float*)&vc)[j - 1];
            const float kt[4] = {kj0, kj1, kj2, kj3};
            const float vt[4] = {vj0, vj1, vj2, vj3};
#pragma unroll
            for (int px = 0; px < 4; ++px) {
                const float bias = is_h ? qbi[px] : qe[px] * r[j];
                const float e = fast_exp2(fmaf(qe[px], kt[px], bias));
                den[px] += e;
                num[px] = fmaf(e, vt[px], num[px]);
            }
        }
    }

    float4 o;
    o.x = num[0] * __builtin_amdgcn_rcpf(den[0]);
    o.y = num[1] * __builtin_amdgcn_rcpf(den[1]);
    o.z = num[2] * __builtin_amdgcn_rcpf(den[2]);
    o.w = num[3] * __builtin_amdgcn_rcpf(den[3]);
    *(float4*)(out + pl * HW + h * W + w0) = o;
}

// ---------------------------------------------------------------------------
extern "C" void kernel_launch(void* const* d_in, const int* in_sizes, int n_in,
                              void* d_out, int out_size, void* d_ws, size_t ws_size,
                              hipStream_t stream)
{
    const float* x     = (const float*)d_in[0];
    const float* Wq    = (const float*)d_in[1];
    const float* Wk    = (const float*)d_in[2];
    const float* Wv    = (const float*)d_in[3];
    const float* rel_h = (const float*)d_in[4];
    const float* rel_w = (const float*)d_in[5];

    float* qb = (float*)d_ws;        // [B,C,64,64]  8 MB
    float* kb = qb + TOT;            // [B,C,64,64]  8 MB
    float* vb = kb + TOT;            // [B,C,64,64]  8 MB

    qkv_mfma<<<B * 128, 256, 0, stream>>>(x, Wq, Wk, Wv, qb, kb, vb);

    attn_kernel<<<B * C * 4, 256, 0, stream>>>(qb, kb, vb, rel_h, rel_w,
                                               (float*)d_out);
}

// Round 21
// 27.517 us; speedup vs baseline: 2.4436x; 2.4436x over previous
//
#include <hip/hip_runtime.h>
#include <hip/hip_bf16.h>

// Problem constants (from reference)
#define B 8
#define C 64
#define H 64
#define W 64
#define K 5
#define PAD 2
#define HW (H * W)          // 4096
#define CHW (C * HW)        // 262144
#define TOT (B * CHW)       // 2097152

// attn tiling (v9): block = 8 rows x 64 cols; 2 px/thread; 4096 blocks
#define TROWS3 8
#define SROWS3 (TROWS3 + 2 * PAD)  // 12 staged rows
#define SCOLS 72                   // 64 + 2*PAD padded to 72 (16B row align)

#define LOG2E 1.44269504088896340736f

typedef __attribute__((ext_vector_type(8))) short short8;   // 8 bf16 = 4 VGPR
typedef __attribute__((ext_vector_type(4))) float f32x4;    // mfma accum

// native bf16 conversion (RNE; pairs lower to v_cvt_pk_bf16_f32)
__device__ inline unsigned short f2bf(float f) {
    __hip_bfloat16 h = __float2bfloat16(f);
    return *(unsigned short*)&h;
}
__device__ inline float bf2f(unsigned short u) {
    return __uint_as_float(((unsigned)u) << 16);
}

// raw v_exp_f32 (single instruction; inputs in [-40,40])
__device__ inline float fast_exp2(float x) {
    return __builtin_amdgcn_exp2f(x);
}

// ---------------------------------------------------------------------------
// Pass 1 (v10): qkv MFMA GEMM — byte-identical to r17 (best: 28.9 us).
// ---------------------------------------------------------------------------
__global__ __launch_bounds__(256) void qkv_mfma(
    const float* __restrict__ x,
    const float* __restrict__ Wq,
    const float* __restrict__ Wk,
    const float* __restrict__ Wv,
    float* __restrict__ qb, float* __restrict__ kb, float* __restrict__ vb)
{
    __shared__ unsigned short sxh[32][72];   // [n][k], 4.6 KB
    __shared__ unsigned short sxl[32][72];

    const int bid = blockIdx.x;
    const int b   = bid & 7;             // XCD co-residency: batch = XCD
    const int n0  = (bid >> 3) * 32;     // hw base (128 chunks per batch)
    const int t   = threadIdx.x;

    const float* xb = x + b * CHW;
#pragma unroll
    for (int i = 0; i < 2; ++i) {
        const int flat = t + i * 256;        // 0..511
        const int k    = flat >> 3;          // 8 float4 per k-row of 32
        const int n4   = (flat & 7) << 2;
        const float4 v = *(const float4*)(xb + k * HW + n0 + n4);
        const float vv[4] = {v.x, v.y, v.z, v.w};
#pragma unroll
        for (int j = 0; j < 4; ++j) {
            const unsigned short h = f2bf(vv[j]);
            sxh[n4 + j][k] = h;
            sxl[n4 + j][k] = f2bf(vv[j] - bf2f(h));
        }
    }
    __syncthreads();

    const int lane = t & 63;
    const int wv   = __builtin_amdgcn_readfirstlane(t >> 6);  // wave id 0..3
    const int lr   = lane & 15;          // tile row (A) / col (B,D)
    const int lk   = (lane >> 4) * 8;    // k-group base

    short8 ah[3][2], al[3][2];
#pragma unroll
    for (int ot = 0; ot < 3; ++ot) {
        const int tile = wv * 3 + ot;            // 0..11
        const int m    = tile >> 2;              // 0=q,1=k,2=v
        const int ol0  = (tile & 3) * 16;        // o base within matrix
        const float* Wm = (m == 0) ? Wq : (m == 1) ? Wk : Wv;
        const float* wrow = Wm + (ol0 + lr) * 64;
#pragma unroll
        for (int ks = 0; ks < 2; ++ks) {
            const float4 w0 = *(const float4*)(wrow + lk + ks * 32);
            const float4 w1 = *(const float4*)(wrow + lk + ks * 32 + 4);
            const float wv8[8] = {w0.x, w0.y, w0.z, w0.w,
                                  w1.x, w1.y, w1.z, w1.w};
            short8 hi, lo;
#pragma unroll
            for (int j = 0; j < 8; ++j) {
                const unsigned short hh = f2bf(wv8[j]);
                hi[j] = (short)hh;
                lo[j] = (short)f2bf(wv8[j] - bf2f(hh));
            }
            ah[ot][ks] = hi;
            al[ot][ks] = lo;
        }
    }

    f32x4 acc[3][2];
#pragma unroll
    for (int ot = 0; ot < 3; ++ot)
#pragma unroll
        for (int nt = 0; nt < 2; ++nt) acc[ot][nt] = (f32x4)0.f;

#pragma unroll
    for (int nt = 0; nt < 2; ++nt) {
        const short8 bh0 = *(const short8*)&sxh[nt * 16 + lr][lk];
        const short8 bh1 = *(const short8*)&sxh[nt * 16 + lr][32 + lk];
        const short8 bl0 = *(const short8*)&sxl[nt * 16 + lr][lk];
        const short8 bl1 = *(const short8*)&sxl[nt * 16 + lr][32 + lk];
#pragma unroll
        for (int ot = 0; ot < 3; ++ot) {
            f32x4 d = acc[ot][nt];
            d = __builtin_amdgcn_mfma_f32_16x16x32_bf16(ah[ot][0], bh0, d, 0, 0, 0);
            d = __builtin_amdgcn_mfma_f32_16x16x32_bf16(ah[ot][1], bh1, d, 0, 0, 0);
            d = __builtin_amdgcn_mfma_f32_16x16x32_bf16(ah[ot][0], bl0, d, 0, 0, 0);
            d = __builtin_amdgcn_mfma_f32_16x16x32_bf16(ah[ot][1], bl1, d, 0, 0, 0);
            d = __builtin_amdgcn_mfma_f32_16x16x32_bf16(al[ot][0], bh0, d, 0, 0, 0);
            d = __builtin_amdgcn_mfma_f32_16x16x32_bf16(al[ot][1], bh1, d, 0, 0, 0);
            acc[ot][nt] = d;
        }
    }

#pragma unroll
    for (int ot = 0; ot < 3; ++ot) {
        const int tile = wv * 3 + ot;
        const int m    = tile >> 2;
        const int ol0  = (tile & 3) * 16;
        float* ob = (m == 0) ? qb : (m == 1) ? kb : vb;
        float* basep = ob + b * CHW + ol0 * HW + n0;
#pragma unroll
        for (int nt = 0; nt < 2; ++nt)
#pragma unroll
            for (int r = 0; r < 4; ++r) {
                const int orow = (lane >> 4) * 4 + r;
                basep[orow * HW + nt * 16 + lr] = acc[ot][nt][r];
            }
    }
}

// ---------------------------------------------------------------------------
// Pass 2 (v9): attn, 2 px/thread.  Live state halved vs r17 (qe[2]/den[2]/
// num[2], three float2 tap reads) -> natural VGPR ~50 -> 8 blocks/CU
// resident WITHOUT launch_bounds coercion (r20's forced bound spilled to
// scratch: VGPR=32, 240 MB of spill traffic).  4096 blocks (8-row tiles)
// = exactly 2 clean resident rounds (was 1.33 ragged at 6 waves/SIMD).
// float2 LDS reads also sit at the b64 structural bank floor (r20 exposed
// 1.65M conflict-cycles on the b128 pattern).  Stage: 768 f2 slots = exactly
// 3/thread (pow-2 mapping, no bounds check); halo ring zero by 96 threads.
// bid = ((c*8+rt)<<3)|b keeps XCD co-residency.
// ---------------------------------------------------------------------------
__global__ __launch_bounds__(256) void attn_kernel(
    const float* __restrict__ qb,
    const float* __restrict__ kb,
    const float* __restrict__ vb,
    const float* __restrict__ rel_h,
    const float* __restrict__ rel_w,
    float* __restrict__ out)
{
    __shared__ __align__(16) float sk[SROWS3][SCOLS];   // 3.5 KB
    __shared__ __align__(16) float sv[SROWS3][SCOLS];   // 3.5 KB

    const int bid = blockIdx.x;
    const int b   = bid & 7;           // XCD co-residency: batch = XCD
    const int u   = bid >> 3;          // 0..511: c*8 + rowtile
    const int c   = u >> 3;
    const int pl  = b * C + c;
    const int h0  = (u & 7) * TROWS3;
    const int t   = threadIdx.x;

    const int lr = t >> 5;             // local row 0..7
    const int w0 = (t & 31) << 1;      // col base 0,2,..,62 (2 px)
    const int h  = h0 + lr;

    // hoisted q load: latency hides under the stage
    const float2 qv = *(const float2*)(qb + pl * HW + h * W + w0);

    const float* kp = kb + pl * HW;
    const float* vp = vb + pl * HW;

    // ---- stage interior: 2 planes * (12 rows x 32 f2) = 768 slots, 3/thr ----
#pragma unroll
    for (int i = 0; i < 3; ++i) {
        const int s  = t + i * 256;          // 0..767
        const int p  = (s >= SROWS3 * 32);
        const int s2 = p ? s - SROWS3 * 32 : s;
        const int row = s2 >> 5;             // 0..11
        const int c2  = s2 & 31;             // f2 slot within row
        const int g   = h0 + row - PAD;      // global row
        float2 val = make_float2(0.f, 0.f);
        if ((unsigned)g < (unsigned)H)
            val = *(const float2*)((p ? vp : kp) + g * W + c2 * 2);
        float* dst = (p ? &sv[0][0] : &sk[0][0]) + row * SCOLS + 2 + c2 * 2;
        *(float2*)dst = val;
    }
    // ---- halo ring zero: cols {0,1},{66..71} of all 12 rows, both planes ----
    if (t < 2 * SROWS3 * 4) {          // 96
        const int p   = (t >= SROWS3 * 4);
        const int s   = p ? t - SROWS3 * 4 : t;
        const int row = s >> 2;              // 0..11
        const int e   = s & 3;               // 0 -> col 0; 1..3 -> 66,68,70
        const int col = (e == 0) ? 0 : (64 + 2 * e);
        float* dst = (p ? &sv[0][0] : &sk[0][0]) + row * SCOLS + col;
        *(float2*)dst = make_float2(0.f, 0.f);
    }
    __syncthreads();

    const float qe[2] = {qv.x * LOG2E, qv.y * LOG2E};

    const bool is_h = (c < (C / 2));
    const float* rp = is_h ? (rel_h + c * K) : (rel_w + (c - C / 2) * K);
    float r[K];
#pragma unroll
    for (int u2 = 0; u2 < K; ++u2) r[u2] = rp[u2];

    float den[2] = {0.f, 0.f};
    float num[2] = {0.f, 0.f};

    // px at global col w0+px; tap j reads LDS col (w0+px)+j  (interior at +2)
    if (is_h) {
#pragma unroll
        for (int i = 0; i < K; ++i) {
            const float2 k0 = *(const float2*)&sk[lr + i][w0];
            const float2 k1 = *(const float2*)&sk[lr + i][w0 + 2];
            const float2 k2 = *(const float2*)&sk[lr + i][w0 + 4];
            const float2 v0 = *(const float2*)&sv[lr + i][w0];
            const float2 v1 = *(const float2*)&sv[lr + i][w0 + 2];
            const float2 v2 = *(const float2*)&sv[lr + i][w0 + 4];
            const float kt[6] = {k0.x, k0.y, k1.x, k1.y, k2.x, k2.y};
            const float vt[6] = {v0.x, v0.y, v1.x, v1.y, v2.x, v2.y};
            const float qri0 = qe[0] * r[i];
            const float qri1 = qe[1] * r[i];
#pragma unroll
            for (int j = 0; j < K; ++j) {
                const float e0 = fast_exp2(fmaf(qe[0], kt[j], qri0));
                den[0] += e0;
                num[0] = fmaf(e0, vt[j], num[0]);
                const float e1 = fast_exp2(fmaf(qe[1], kt[j + 1], qri1));
                den[1] += e1;
                num[1] = fmaf(e1, vt[j + 1], num[1]);
            }
        }
    } else {
#pragma unroll
        for (int i = 0; i < K; ++i) {
            const float2 k0 = *(const float2*)&sk[lr + i][w0];
            const float2 k1 = *(const float2*)&sk[lr + i][w0 + 2];
            const float2 k2 = *(const float2*)&sk[lr + i][w0 + 4];
            const float2 v0 = *(const float2*)&sv[lr + i][w0];
            const float2 v1 = *(const float2*)&sv[lr + i][w0 + 2];
            const float2 v2 = *(const float2*)&sv[lr + i][w0 + 4];
            const float kt[6] = {k0.x, k0.y, k1.x, k1.y, k2.x, k2.y};
            const float vt[6] = {v0.x, v0.y, v1.x, v1.y, v2.x, v2.y};
#pragma unroll
            for (int j = 0; j < K; ++j) {
                const float qrj0 = qe[0] * r[j];
                const float qrj1 = qe[1] * r[j];
                const float e0 = fast_exp2(fmaf(qe[0], kt[j], qrj0));
                den[0] += e0;
                num[0] = fmaf(e0, vt[j], num[0]);
                const float e1 = fast_exp2(fmaf(qe[1], kt[j + 1], qrj1));
                den[1] += e1;
                num[1] = fmaf(e1, vt[j + 1], num[1]);
            }
        }
    }

    float2 o;
    o.x = num[0] * __builtin_amdgcn_rcpf(den[0]);
    o.y = num[1] * __builtin_amdgcn_rcpf(den[1]);
    *(float2*)(out + pl * HW + h * W + w0) = o;
}

// ---------------------------------------------------------------------------
extern "C" void kernel_launch(void* const* d_in, const int* in_sizes, int n_in,
                              void* d_out, int out_size, void* d_ws, size_t ws_size,
                              hipStream_t stream)
{
    const float* x     = (const float*)d_in[0];
    const float* Wq    = (const float*)d_in[1];
    const float* Wk    = (const float*)d_in[2];
    const float* Wv    = (const float*)d_in[3];
    const float* rel_h = (const float*)d_in[4];
    const float* rel_w = (const float*)d_in[5];

    float* qb = (float*)d_ws;        // [B,C,64,64]  8 MB
    float* kb = qb + TOT;            // [B,C,64,64]  8 MB
    float* vb = kb + TOT;            // [B,C,64,64]  8 MB

    qkv_mfma<<<B * 128, 256, 0, stream>>>(x, Wq, Wk, Wv, qb, kb, vb);

    attn_kernel<<<B * C * 8, 256, 0, stream>>>(qb, kb, vb, rel_h, rel_w,
                                               (float*)d_out);
}